// Round 4
// baseline (2351.314 us; speedup 1.0000x reference)
//
#include <hip/hip_runtime.h>
#include <hip/hip_bf16.h>
#include <stdint.h>

#define B_  256
#define T_  128
#define E_  256
#define H_  512
#define G4  2048
#define U1_ 256
#define U2_ 64

#define NWG 256   // (hidden-slice 0..127) x (batch-half 0..1)
#define MS  4     // hidden indices per slice

// h fragment buffer: [btile(16)][kc(16)][lane(64)][e(8)] bf16 = 256 KB per buffer
#define HFRAG_SHORTS (16 * 16 * 64 * 8)
// x fragment buffer per step: [btile(16)][kc(8)][lane(64)][e(8)] bf16 = 128 KB
#define XFRAG_SHORTS (16 * 8 * 64 * 8)

typedef __attribute__((ext_vector_type(8))) short bf16x8;
typedef __attribute__((ext_vector_type(4))) float f32x4;
typedef unsigned long long ull;

static __device__ __forceinline__ unsigned short f2bf(float f) {
    unsigned u = __float_as_uint(f);
    unsigned r = (u + 0x7FFFu + ((u >> 16) & 1u)) >> 16;   // RNE
    return (unsigned short)r;
}

// ---------- A1: gather embeddings -> x in MFMA B-frag layout (bf16) ----------
// B-frag for (btile, kc): lane l holds x[btile*16 + (l&15)][kc*32 + (l>>4)*8 + e]
__global__ __launch_bounds__(256) void k_gather(const int* __restrict__ inp,
                                                const float* __restrict__ emb,
                                                short* __restrict__ xfrag) {
    const int tid  = threadIdx.x;
    const int wv   = tid >> 6;
    const int lane = tid & 63;
    const int c16  = lane & 15;
    const int g4   = lane >> 4;
    for (int it = 0; it < 16; ++it) {
        int task  = (it * 256 + blockIdx.x) * 4 + wv;   // 0..16383 = t*128 + btile*8 + kc
        int kc    = task & 7;
        int btile = (task >> 3) & 15;
        int t     = task >> 7;
        int b     = btile * 16 + c16;
        int idx   = inp[b * T_ + t];
        const float* src = emb + (long)idx * E_ + kc * 32 + g4 * 8;
        float4 v0 = *(const float4*)src;
        float4 v1 = *(const float4*)(src + 4);
        bf16x8 o;
        o[0]=(short)f2bf(v0.x); o[1]=(short)f2bf(v0.y); o[2]=(short)f2bf(v0.z); o[3]=(short)f2bf(v0.w);
        o[4]=(short)f2bf(v1.x); o[5]=(short)f2bf(v1.y); o[6]=(short)f2bf(v1.z); o[7]=(short)f2bf(v1.w);
        // coalesced: 64 lanes write 1KB contiguous
        *(bf16x8*)(xfrag + ((long)((t * 16 + btile) * 8 + kc) * 64 + lane) * 8) = o;
    }
}

// ---------------- B: persistent recurrent kernel ----------------
// 256 WGs x 512 threads (8 waves). WG = (hidden-slice hs, batch-half bh); wave
// wv owns batch tile btile = bh*8+wv (16 rows). Per step:
//   acc = bias + x-GEMM (prefetched, BEFORE the wait — hides under sync),
//   wait(flags) -> acquire fence -> h-GEMM (16 frag loads) -> gates ->
//   publish h-frags (agent-scope 8B stores) -> barrier -> flag store.
__global__ __launch_bounds__(512, 1) void k_lstm(
    const float* __restrict__ U,      // [H_][G4]
    const float* __restrict__ W,      // [E_][G4]
    const float* __restrict__ bias,   // [G4]
    const short* __restrict__ xfrag,  // [T_][16][8][64][8] bf16
    short* hfrag,                     // [2][16][16][64][8] bf16 (double buffer)
    unsigned int* flags,              // [NWG*32] per-WG step flags (128B spaced)
    float* hfin)                      // [B_][H_] f32
{
    const int tid   = threadIdx.x;
    const int wid   = blockIdx.x;       // 0..255
    const int hs    = wid >> 1;         // hidden slice 0..127
    const int bh    = wid & 1;          // batch half
    const int m0    = hs * MS;
    const int lane  = tid & 63;
    const int wv    = tid >> 6;         // wave 0..7
    const int c16   = lane & 15;
    const int g4    = lane >> 4;
    const int btile = bh * 8 + wv;      // this wave's batch tile (16 rows)

    // A-frag row r = c16 -> j = gate(r)*H + m0 + (r&3)
    const int jA = ((c16 >> 2) * H_) + m0 + (c16 & 3);

    // Prologue: pack U/W slices into persistent MFMA A-fragments (registers).
    bf16x8 a_u[16];
    #pragma unroll
    for (int kc = 0; kc < 16; ++kc) {
        int kbase = kc * 32 + g4 * 8;
        bf16x8 a;
        #pragma unroll
        for (int e = 0; e < 8; ++e) a[e] = (short)f2bf(U[(long)(kbase + e) * G4 + jA]);
        a_u[kc] = a;
    }
    bf16x8 a_w[8];
    #pragma unroll
    for (int kc = 0; kc < 8; ++kc) {
        int kbase = kc * 32 + g4 * 8;
        bf16x8 a;
        #pragma unroll
        for (int e = 0; e < 8; ++e) a[e] = (short)f2bf(W[(long)(kbase + e) * G4 + jA]);
        a_w[kc] = a;
    }
    float bq[4];
    #pragma unroll
    for (int q = 0; q < 4; ++q) bq[q] = bias[g4 * H_ + m0 + q];

    float cst[4] = {0.f, 0.f, 0.f, 0.f};   // cell state (redundant across groups)

    // publish address components (constant per thread)
    const int kcw  = m0 >> 5;                         // h k-block of this WG
    const int lpos = ((m0 & 31) >> 3) * 16 + c16;     // lane slot within frag block
    const int e0   = m0 & 7;                          // element offset (0 or 4)

    for (int t = 0; t < T_; ++t) {
        const short* xr = xfrag + (long)t * XFRAG_SHORTS + lane * 8;

        // x phase (h-independent): prefetch + MFMA BEFORE the wait.
        bf16x8 xp[8];
        #pragma unroll
        for (int kc = 0; kc < 8; ++kc)
            xp[kc] = *(const bf16x8*)(xr + (long)(btile * 8 + kc) * 512);

        f32x4 acc = (f32x4){bq[0], bq[1], bq[2], bq[3]};
        #pragma unroll
        for (int kc = 0; kc < 8; ++kc)
            acc = __builtin_amdgcn_mfma_f32_16x16x32_bf16(a_w[kc], xp[kc], acc, 0, 0, 0);

        if (t > 0) {
            if (tid < NWG) {
                unsigned iter = 0;
                while (__hip_atomic_load(&flags[tid * 32], __ATOMIC_RELAXED,
                                         __HIP_MEMORY_SCOPE_AGENT) < (unsigned)t) {
                    __builtin_amdgcn_s_sleep(2);
                    if (++iter > (1u << 22)) break;   // fail loud, never hang
                }
            }
            __syncthreads();
            __builtin_amdgcn_fence(__ATOMIC_ACQUIRE, "agent");   // buffer_inv
        }
        const short* hr = hfrag + (long)((t & 1) ^ 1) * HFRAG_SHORTS + lane * 8;

        // z += U^T(slice) @ h^T   (K = 512) — coalesced frag loads
        #pragma unroll
        for (int kc = 0; kc < 16; ++kc) {
            bf16x8 bfr = *(const bf16x8*)(hr + (long)(btile * 16 + kc) * 512);
            acc = __builtin_amdgcn_mfma_f32_16x16x32_bf16(a_u[kc], bfr, acc, 0, 0, 0);
        }

        // Gates: lane group g4 owns gate g4 (rows g4*4+q). Apply own activation,
        // shuffle so every lane gets (i,f,g,o) for (q, col c16).
        float hval[4];
        #pragma unroll
        for (int q = 0; q < 4; ++q) {
            float z = acc[q];
            float a = (g4 == 2) ? fmaxf(z, 0.f)               // candidate: relu
                                : 1.f / (1.f + __expf(-z));   // i,f,o: sigmoid
            float ai = __shfl(a, c16,      64);
            float af = __shfl(a, c16 + 16, 64);
            float ag = __shfl(a, c16 + 32, 64);
            float ao = __shfl(a, c16 + 48, 64);
            float c_ = af * cst[q] + ai * ag;
            cst[q] = c_;
            hval[q] = ao * fmaxf(c_, 0.f);
        }

        if (t < T_ - 1) {
            // Publish into frag layout (group 0 publishes; all groups redundant).
            short* hw = hfrag + (long)(t & 1) * HFRAG_SHORTS;
            if (lane < 16) {
                ull pk =  (ull)f2bf(hval[0])
                       | ((ull)f2bf(hval[1]) << 16)
                       | ((ull)f2bf(hval[2]) << 32)
                       | ((ull)f2bf(hval[3]) << 48);
                __hip_atomic_store(
                    (ull*)(hw + (long)(btile * 16 + kcw) * 512 + lpos * 8 + e0),
                    pk, __ATOMIC_RELAXED, __HIP_MEMORY_SCOPE_AGENT);
            }
            __syncthreads();      // drains vmcnt for ALL waves' h-stores
            if (tid == 0) {
                __hip_atomic_store(&flags[wid * 32], (unsigned)(t + 1),
                                   __ATOMIC_RELAXED, __HIP_MEMORY_SCOPE_AGENT);
            }
        } else {
            if (lane < 16) {
                float4 pk = make_float4(hval[0], hval[1], hval[2], hval[3]);
                *(float4*)(hfin + (long)(btile * 16 + lane) * H_ + m0) = pk;
            }
        }
    }
}

// ---------------- C: dense head + softmax ----------------
__global__ __launch_bounds__(256) void k_head(const float* __restrict__ hfin,
                                              const float* __restrict__ W2,
                                              const float* __restrict__ b2,
                                              const float* __restrict__ W3,
                                              const float* __restrict__ b3,
                                              float* __restrict__ out) {
    __shared__ float hs[H_];
    __shared__ float ys[U1_];
    __shared__ float ps[4][U2_];
    const int b = blockIdx.x, tid = threadIdx.x;
    if (tid < 128) *(float4*)(hs + tid * 4) = *(const float4*)(hfin + (long)b * H_ + tid * 4);
    __syncthreads();
    float acc = b2[tid];
    #pragma unroll 8
    for (int k = 0; k < H_; ++k) acc += hs[k] * W2[(long)k * U1_ + tid];
    ys[tid] = fmaxf(acc, 0.f);
    __syncthreads();
    const int u2 = tid & 63, part = tid >> 6;
    float p = 0.f;
    #pragma unroll 8
    for (int k = part * 64; k < part * 64 + 64; ++k) p += ys[k] * W3[(long)k * U2_ + u2];
    ps[part][u2] = p;
    __syncthreads();
    if (tid < 64) {
        float lg = b3[tid] + ps[0][tid] + ps[1][tid] + ps[2][tid] + ps[3][tid];
        float m = lg;
        #pragma unroll
        for (int off = 32; off >= 1; off >>= 1) m = fmaxf(m, __shfl_xor(m, off, 64));
        float e = __expf(lg - m);
        float s = e;
        #pragma unroll
        for (int off = 32; off >= 1; off >>= 1) s += __shfl_xor(s, off, 64);
        out[(long)b * U2_ + tid] = e / s;
    }
}

extern "C" void kernel_launch(void* const* d_in, const int* in_sizes, int n_in,
                              void* d_out, int out_size, void* d_ws, size_t ws_size,
                              hipStream_t stream) {
    const int*   inp = (const int*)d_in[0];
    const float* emb = (const float*)d_in[1];
    const float* W   = (const float*)d_in[2];
    const float* U   = (const float*)d_in[3];
    const float* bb  = (const float*)d_in[4];
    const float* W2  = (const float*)d_in[5];
    const float* b2  = (const float*)d_in[6];
    const float* W3  = (const float*)d_in[7];
    const float* b3  = (const float*)d_in[8];

    char* ws = (char*)d_ws;
    short*        hfrag = (short*)ws;                                  // 2 * 256 KiB
    unsigned int* flags = (unsigned int*)(ws + 524288);                // 32 KiB (128B/WG)
    short*        xfrag = (short*)(ws + (1 << 20));                    // 16 MiB
    float*        hfin  = (float*)(ws + (1 << 20) + (long)T_ * XFRAG_SHORTS * 2); // 512 KiB

    // zero h(-1) double-buffer + per-WG flags (replay-deterministic)
    hipMemsetAsync(ws, 0, 524288 + 32768, stream);
    k_gather<<<256, 256, 0, stream>>>(inp, emb, xfrag);
    k_lstm<<<NWG, 512, 0, stream>>>(U, W, bb, xfrag, hfrag, flags, hfin);
    k_head<<<B_, 256, 0, stream>>>(hfin, W2, b2, W3, b3, (float*)d_out);
}

// Round 5
// 1184.387 us; speedup vs baseline: 1.9853x; 1.9853x over previous
//
#include <hip/hip_runtime.h>
#include <hip/hip_bf16.h>
#include <stdint.h>

#define B_  256
#define T_  128
#define E_  256
#define H_  512
#define G4  2048
#define U1_ 256
#define U2_ 64

#define HB_STEP   (16 * 16 * 64 * 8)   // shorts per h step-buffer (256 KB)
#define XF_STEP   (16 * 8 * 64 * 8)    // shorts per x step (128 KB)
#define SGN 0x8000800080008000ULL

typedef __attribute__((ext_vector_type(8))) short bf16x8;
typedef __attribute__((ext_vector_type(4))) float f32x4;
typedef __attribute__((ext_vector_type(2))) unsigned long long ullx2;
typedef unsigned long long ull;

static __device__ __forceinline__ unsigned short f2bf(float f) {
    unsigned u = __float_as_uint(f);
    unsigned r = (u + 0x7FFFu + ((u >> 16) & 1u)) >> 16;   // RNE
    return (unsigned short)r;
}
static __device__ __forceinline__ ull ald(const ull* p) {
    return __hip_atomic_load(p, __ATOMIC_RELAXED, __HIP_MEMORY_SCOPE_AGENT);
}
static __device__ __forceinline__ void ast(ull* p, ull v) {
    __hip_atomic_store(p, v, __ATOMIC_RELAXED, __HIP_MEMORY_SCOPE_AGENT);
}

// ---------- A0: pack U,W (f32 row-major) into bf16 MFMA A-frag layout ----------
// wpk[(hs*2+blk)*24 + kc][lane(64)][e(8)]: lane (c16,g4), elem e holds
// src[kc*32 + g4*8 + e][ (c16>>2)*512 + hs*8 + blk*4 + (c16&3) ]
__global__ __launch_bounds__(256) void k_prep(const float* __restrict__ U,
                                              const float* __restrict__ W,
                                              short* __restrict__ wpk) {
    __shared__ float ld[32][64];
    const int bj = blockIdx.x;          // 0..31: (gate, 64-wide j window)
    const int g  = bj >> 3;
    const int l0 = (bj & 7) * 64;
    const int t  = threadIdx.x;
    const int p   = t >> 4;             // 0..15 -> (hs_local, blk)
    const int hsl = p >> 1, blk = p & 1;
    const int ci  = t & 3;
    const int g4w = (t >> 2) & 3;
    const int hs  = (l0 >> 3) + hsl;
    const int c16 = g * 4 + ci;
    const int jloc = hsl * 8 + blk * 4 + ci;
    for (int kc = 0; kc < 24; ++kc) {
        const float* src = (kc < 16) ? (U + (long)(kc * 32) * G4)
                                     : (W + (long)((kc - 16) * 32) * G4);
        #pragma unroll
        for (int r = 0; r < 8; ++r) {
            int row = r * 4 + (t >> 6);
            ld[row][t & 63] = src[(long)row * G4 + g * 512 + l0 + (t & 63)];
        }
        __syncthreads();
        bf16x8 o;
        #pragma unroll
        for (int e = 0; e < 8; ++e) o[e] = (short)f2bf(ld[g4w * 8 + e][jloc]);
        *(bf16x8*)(wpk + (((long)(hs * 2 + blk) * 24 + kc) * 64 + (g4w * 16 + c16)) * 8) = o;
        __syncthreads();
    }
}

// ---------- A1: gather embeddings -> x in MFMA B-frag layout (bf16) ----------
__global__ __launch_bounds__(256) void k_gather(const int* __restrict__ inp,
                                                const float* __restrict__ emb,
                                                short* __restrict__ xfrag) {
    const int tid  = threadIdx.x;
    const int wv   = tid >> 6;
    const int lane = tid & 63;
    const int c16  = lane & 15;
    const int g4   = lane >> 4;
    for (int it = 0; it < 16; ++it) {
        int task  = (it * 256 + blockIdx.x) * 4 + wv;   // t*128 + btile*8 + kc
        int kc    = task & 7;
        int btile = (task >> 3) & 15;
        int t     = task >> 7;
        int b     = btile * 16 + c16;
        int idx   = inp[b * T_ + t];
        const float* src = emb + (long)idx * E_ + kc * 32 + g4 * 8;
        float4 v0 = *(const float4*)src;
        float4 v1 = *(const float4*)(src + 4);
        bf16x8 o;
        o[0]=(short)f2bf(v0.x); o[1]=(short)f2bf(v0.y); o[2]=(short)f2bf(v0.z); o[3]=(short)f2bf(v0.w);
        o[4]=(short)f2bf(v1.x); o[5]=(short)f2bf(v1.y); o[6]=(short)f2bf(v1.z); o[7]=(short)f2bf(v1.w);
        *(bf16x8*)(xfrag + ((long)((t * 16 + btile) * 8 + kc) * 64 + lane) * 8) = o;
    }
}

// ---------------- B: persistent recurrent kernel, pure dataflow ----------------
// No flags, no fences, no barriers. h lives in a T-deep write-once frag buffer,
// 0xAA-poisoned each launch. h >= 0 always (sigmoid * relu), so a clear bf16
// sign bit == fresh data; poison has all sign bits set. Producers publish with
// relaxed agent-scope 8B stores (write-through to L3); consumers poll the data
// itself with agent-scope loads (bypass stale L1/L2) and feed the polled
// registers directly into MFMA. Fixed kc processing order keeps fp math
// deterministic.
__global__ __launch_bounds__(256, 1) void k_lstm(
    const float* __restrict__ bias,   // [G4]
    const short* __restrict__ wpk,    // packed A-frags
    const short* __restrict__ xfrag,  // [T_][16][8][64][8] bf16
    short* hfrag,                     // [T_-1][16][16][64][8] bf16, poisoned
    float* hfin)                      // [B_][H_] f32
{
    const int tid  = threadIdx.x;
    const int wid  = blockIdx.x;      // 0..255
    const int hs   = wid >> 2;        // hidden slice 0..63 (8 units)
    const int bq   = wid & 3;         // batch quarter
    const int lane = tid & 63;
    const int wv   = tid >> 6;
    const int bt   = bq * 4 + wv;     // this wave's batch tile (16 rows)
    const int c16  = lane & 15;
    const int g4   = lane >> 4;

    // Persistent A-frags, coalesced load from wpk (2 j-blocks x (16 U + 8 W))
    bf16x8 a_u[2][16], a_w[2][8];
    #pragma unroll
    for (int blk = 0; blk < 2; ++blk) {
        #pragma unroll
        for (int kc = 0; kc < 16; ++kc)
            a_u[blk][kc] = *(const bf16x8*)(wpk + (((long)(hs*2+blk)*24 + kc)*64 + lane)*8);
        #pragma unroll
        for (int kc = 0; kc < 8; ++kc)
            a_w[blk][kc] = *(const bf16x8*)(wpk + (((long)(hs*2+blk)*24 + 16 + kc)*64 + lane)*8);
    }
    float b0[4], b1[4];
    #pragma unroll
    for (int q = 0; q < 4; ++q) {
        b0[q] = bias[g4 * H_ + hs * 8 + q];
        b1[q] = bias[g4 * H_ + hs * 8 + 4 + q];
    }
    float cst[8];
    #pragma unroll
    for (int i = 0; i < 8; ++i) cst[i] = 0.f;

    // publish slot: frag (bt, kc=hs>>2), lane slot (hs&3)*16 + c16, 16B/row
    ull* const pub0 = (ull*)hfrag +
        (((long)bt * 16 + (hs >> 2)) * 64 + ((hs & 3) * 16 + c16)) * 2;

    for (int t = 0; t < T_; ++t) {
        // x B-frags: plain cached loads, issued FIRST (complete first in FIFO)
        const short* xr = xfrag + (long)t * XF_STEP;
        bf16x8 xf[8];
        #pragma unroll
        for (int kc = 0; kc < 8; ++kc)
            xf[kc] = *(const bf16x8*)(xr + ((long)(bt * 8 + kc) * 64 + lane) * 8);

        // h poll-loads: issue all 16 frags (2x8B each), overlap with x-GEMM
        ull L[16], Hh[16];
        const ull* hp = (const ull*)(hfrag + (long)(t - 1) * HB_STEP) +
                        ((long)bt * 16 * 64 + lane) * 2;
        if (t > 0) {
            #pragma unroll
            for (int kc = 0; kc < 16; ++kc) {
                L[kc]  = ald(hp + kc * 128);
                Hh[kc] = ald(hp + kc * 128 + 1);
            }
        }

        f32x4 a0 = (f32x4){b0[0], b0[1], b0[2], b0[3]};
        f32x4 a1 = (f32x4){b1[0], b1[1], b1[2], b1[3]};
        #pragma unroll
        for (int kc = 0; kc < 8; ++kc) {
            a0 = __builtin_amdgcn_mfma_f32_16x16x32_bf16(a_w[0][kc], xf[kc], a0, 0, 0, 0);
            a1 = __builtin_amdgcn_mfma_f32_16x16x32_bf16(a_w[1][kc], xf[kc], a1, 0, 0, 0);
        }

        if (t > 0) {
            #pragma unroll
            for (int kc = 0; kc < 16; ++kc) {
                int guard = 0;
                while (!__all(((L[kc] | Hh[kc]) & SGN) == 0)) {   // fresh iff all sign bits clear
                    L[kc]  = ald(hp + kc * 128);
                    Hh[kc] = ald(hp + kc * 128 + 1);
                    if (++guard > (1 << 22)) break;   // fail loud, never hang
                }
                ullx2 u; u[0] = L[kc]; u[1] = Hh[kc];
                bf16x8 hf = __builtin_bit_cast(bf16x8, u);
                a0 = __builtin_amdgcn_mfma_f32_16x16x32_bf16(a_u[0][kc], hf, a0, 0, 0, 0);
                a1 = __builtin_amdgcn_mfma_f32_16x16x32_bf16(a_u[1][kc], hf, a1, 0, 0, 0);
            }
        }

        // Gates: lane group g4 owns gate g4; shuffle activated values so every
        // lane gets (i,f,g,o) for its (q, batch col c16) of both j-blocks.
        float hv[8];
        #pragma unroll
        for (int blk = 0; blk < 2; ++blk) {
            #pragma unroll
            for (int q = 0; q < 4; ++q) {
                float z = blk ? a1[q] : a0[q];
                float a = (g4 == 2) ? fmaxf(z, 0.f)               // candidate: relu
                                    : 1.f / (1.f + __expf(-z));   // i,f,o: sigmoid
                float ai = __shfl(a, c16,      64);
                float af = __shfl(a, c16 + 16, 64);
                float ag = __shfl(a, c16 + 32, 64);
                float ao = __shfl(a, c16 + 48, 64);
                float c_ = af * cst[blk*4+q] + ai * ag;
                cst[blk*4+q] = c_;
                hv[blk*4+q] = ao * fmaxf(c_, 0.f);
            }
        }

        if (t < T_ - 1) {
            if (g4 == 0) {   // 16 lanes publish 16B each: full-density 256B block
                ull p0 = (ull)f2bf(hv[0]) | ((ull)f2bf(hv[1])<<16)
                       | ((ull)f2bf(hv[2])<<32) | ((ull)f2bf(hv[3])<<48);
                ull p1 = (ull)f2bf(hv[4]) | ((ull)f2bf(hv[5])<<16)
                       | ((ull)f2bf(hv[6])<<32) | ((ull)f2bf(hv[7])<<48);
                ull* d = pub0 + (long)t * (HB_STEP / 4);
                ast(d, p0); ast(d + 1, p1);
            }
        } else {
            if (g4 == 0) {
                *(float4*)(hfin + ((long)bt * 16 + c16) * H_ + hs * 8)
                    = make_float4(hv[0], hv[1], hv[2], hv[3]);
                *(float4*)(hfin + ((long)bt * 16 + c16) * H_ + hs * 8 + 4)
                    = make_float4(hv[4], hv[5], hv[6], hv[7]);
            }
        }
    }
}

// ---------------- C: dense head + softmax ----------------
__global__ __launch_bounds__(256) void k_head(const float* __restrict__ hfin,
                                              const float* __restrict__ W2,
                                              const float* __restrict__ b2,
                                              const float* __restrict__ W3,
                                              const float* __restrict__ b3,
                                              float* __restrict__ out) {
    __shared__ float hs[H_];
    __shared__ float ys[U1_];
    __shared__ float ps[4][U2_];
    const int b = blockIdx.x, tid = threadIdx.x;
    if (tid < 128) *(float4*)(hs + tid * 4) = *(const float4*)(hfin + (long)b * H_ + tid * 4);
    __syncthreads();
    float acc = b2[tid];
    #pragma unroll 8
    for (int k = 0; k < H_; ++k) acc += hs[k] * W2[(long)k * U1_ + tid];
    ys[tid] = fmaxf(acc, 0.f);
    __syncthreads();
    const int u2 = tid & 63, part = tid >> 6;
    float p = 0.f;
    #pragma unroll 8
    for (int k = part * 64; k < part * 64 + 64; ++k) p += ys[k] * W3[(long)k * U2_ + u2];
    ps[part][u2] = p;
    __syncthreads();
    if (tid < 64) {
        float lg = b3[tid] + ps[0][tid] + ps[1][tid] + ps[2][tid] + ps[3][tid];
        float m = lg;
        #pragma unroll
        for (int off = 32; off >= 1; off >>= 1) m = fmaxf(m, __shfl_xor(m, off, 64));
        float e = __expf(lg - m);
        float s = e;
        #pragma unroll
        for (int off = 32; off >= 1; off >>= 1) s += __shfl_xor(s, off, 64);
        out[(long)b * U2_ + tid] = e / s;
    }
}

extern "C" void kernel_launch(void* const* d_in, const int* in_sizes, int n_in,
                              void* d_out, int out_size, void* d_ws, size_t ws_size,
                              hipStream_t stream) {
    const int*   inp = (const int*)d_in[0];
    const float* emb = (const float*)d_in[1];
    const float* W   = (const float*)d_in[2];
    const float* U   = (const float*)d_in[3];
    const float* bb  = (const float*)d_in[4];
    const float* W2  = (const float*)d_in[5];
    const float* b2  = (const float*)d_in[6];
    const float* W3  = (const float*)d_in[7];
    const float* b3  = (const float*)d_in[8];

    char* ws = (char*)d_ws;
    const long HB_BYTES = (long)(T_ - 1) * HB_STEP * 2;      // 33,292,288
    short* hfrag = (short*)ws;                                // [0, 31.75MB)
    short* xfrag = (short*)(ws + HB_BYTES);                   // 16 MiB
    short* wpk   = (short*)(ws + HB_BYTES + 16777216);        // 3 MiB
    float* hfin  = (float*)(ws + HB_BYTES + 16777216 + 3145728); // 512 KiB

    // re-poison the write-once h buffers every call (determinism across replays)
    hipMemsetAsync(hfrag, 0xAA, HB_BYTES, stream);
    k_prep<<<32, 256, 0, stream>>>(U, W, wpk);
    k_gather<<<256, 256, 0, stream>>>(inp, emb, xfrag);
    k_lstm<<<256, 256, 0, stream>>>(bb, wpk, xfrag, hfrag, hfin);
    k_head<<<B_, 256, 0, stream>>>(hfin, W2, b2, W3, b3, (float*)d_out);
}

// Round 6
// 1051.059 us; speedup vs baseline: 2.2371x; 1.1269x over previous
//
#include <hip/hip_runtime.h>
#include <hip/hip_bf16.h>
#include <stdint.h>

#define B_  256
#define T_  128
#define E_  256
#define H_  512
#define G4  2048
#define U1_ 256
#define U2_ 64

#define HB_STEP   (16 * 16 * 64 * 8)   // shorts per h step-buffer (256 KB)
#define XF_STEP   (16 * 8 * 64 * 8)    // shorts per x step (128 KB)
#define SGN 0x8000800080008000ULL

typedef __attribute__((ext_vector_type(8))) short bf16x8;
typedef __attribute__((ext_vector_type(4))) float f32x4;
typedef __attribute__((ext_vector_type(2))) unsigned long long ullx2;
typedef unsigned long long ull;

static __device__ __forceinline__ unsigned short f2bf(float f) {
    unsigned u = __float_as_uint(f);
    unsigned r = (u + 0x7FFFu + ((u >> 16) & 1u)) >> 16;   // RNE
    return (unsigned short)r;
}
static __device__ __forceinline__ ull ald(const ull* p) {
    return __hip_atomic_load(p, __ATOMIC_RELAXED, __HIP_MEMORY_SCOPE_AGENT);
}
static __device__ __forceinline__ void ast(ull* p, ull v) {
    __hip_atomic_store(p, v, __ATOMIC_RELAXED, __HIP_MEMORY_SCOPE_AGENT);
}

// ---------- A0: pack U,W (f32 row-major) into bf16 MFMA A-frag layout ----------
// wpk[(hs*2+blk)*24 + kc][lane(64)][e(8)]: lane (c16,g4), elem e holds
// src[kc*32 + g4*8 + e][ (c16>>2)*512 + hs*8 + blk*4 + (c16&3) ]
__global__ __launch_bounds__(256) void k_prep(const float* __restrict__ U,
                                              const float* __restrict__ W,
                                              short* __restrict__ wpk) {
    __shared__ float ld[32][64];
    const int bj = blockIdx.x;          // 0..31: (gate, 64-wide j window)
    const int g  = bj >> 3;
    const int l0 = (bj & 7) * 64;
    const int t  = threadIdx.x;
    const int p   = t >> 4;             // 0..15 -> (hs_local, blk)
    const int hsl = p >> 1, blk = p & 1;
    const int ci  = t & 3;
    const int g4w = (t >> 2) & 3;
    const int hs  = (l0 >> 3) + hsl;
    const int c16 = g * 4 + ci;
    const int jloc = hsl * 8 + blk * 4 + ci;
    for (int kc = 0; kc < 24; ++kc) {
        const float* src = (kc < 16) ? (U + (long)(kc * 32) * G4)
                                     : (W + (long)((kc - 16) * 32) * G4);
        #pragma unroll
        for (int r = 0; r < 8; ++r) {
            int row = r * 4 + (t >> 6);
            ld[row][t & 63] = src[(long)row * G4 + g * 512 + l0 + (t & 63)];
        }
        __syncthreads();
        bf16x8 o;
        #pragma unroll
        for (int e = 0; e < 8; ++e) o[e] = (short)f2bf(ld[g4w * 8 + e][jloc]);
        *(bf16x8*)(wpk + (((long)(hs * 2 + blk) * 24 + kc) * 64 + (g4w * 16 + c16)) * 8) = o;
        __syncthreads();
    }
}

// ---------- A1: gather embeddings -> x in MFMA B-frag layout (bf16) ----------
__global__ __launch_bounds__(256) void k_gather(const int* __restrict__ inp,
                                                const float* __restrict__ emb,
                                                short* __restrict__ xfrag) {
    const int tid  = threadIdx.x;
    const int wv   = tid >> 6;
    const int lane = tid & 63;
    const int c16  = lane & 15;
    const int g4   = lane >> 4;
    for (int it = 0; it < 16; ++it) {
        int task  = (it * 256 + blockIdx.x) * 4 + wv;   // t*128 + btile*8 + kc
        int kc    = task & 7;
        int btile = (task >> 3) & 15;
        int t     = task >> 7;
        int b     = btile * 16 + c16;
        int idx   = inp[b * T_ + t];
        const float* src = emb + (long)idx * E_ + kc * 32 + g4 * 8;
        float4 v0 = *(const float4*)src;
        float4 v1 = *(const float4*)(src + 4);
        bf16x8 o;
        o[0]=(short)f2bf(v0.x); o[1]=(short)f2bf(v0.y); o[2]=(short)f2bf(v0.z); o[3]=(short)f2bf(v0.w);
        o[4]=(short)f2bf(v1.x); o[5]=(short)f2bf(v1.y); o[6]=(short)f2bf(v1.z); o[7]=(short)f2bf(v1.w);
        *(bf16x8*)(xfrag + ((long)((t * 16 + btile) * 8 + kc) * 64 + lane) * 8) = o;
    }
}

// ---------------- B: persistent recurrent kernel, pure dataflow ----------------
// No flags, no fences, no barriers. h lives in a T-deep write-once frag buffer,
// 0xAA-poisoned each launch. h >= 0 always (sigmoid * relu), so "all bf16 sign
// bits clear" == fresh data at ANY tearing granularity (old bytes have sign
// set). Producers publish with relaxed agent-scope 8B stores (write-through to
// the coherence point); consumers poll the data itself with agent-scope loads.
// Detection is BATCHED: re-issue loads for all still-stale frags each spin
// iteration so round-trips overlap (round-4 bug: serial per-frag spins cost 16
// dependent RTs). Fixed kc order keeps fp math deterministic.
__global__ __launch_bounds__(256, 1) void k_lstm(
    const float* __restrict__ bias,   // [G4]
    const short* __restrict__ wpk,    // packed A-frags
    const short* __restrict__ xfrag,  // [T_][16][8][64][8] bf16
    short* hfrag,                     // [T_-1][16][16][64][8] bf16, poisoned
    float* hfin)                      // [B_][H_] f32
{
    const int tid  = threadIdx.x;
    const int wid  = blockIdx.x;      // 0..255
    const int hs   = wid >> 2;        // hidden slice 0..63 (8 units)
    const int bq   = wid & 3;         // batch quarter
    const int lane = tid & 63;
    const int wv   = tid >> 6;
    const int bt   = bq * 4 + wv;     // this wave's batch tile (16 rows)
    const int c16  = lane & 15;
    const int g4   = lane >> 4;

    // Persistent A-frags, coalesced load from wpk (2 j-blocks x (16 U + 8 W))
    bf16x8 a_u[2][16], a_w[2][8];
    #pragma unroll
    for (int blk = 0; blk < 2; ++blk) {
        #pragma unroll
        for (int kc = 0; kc < 16; ++kc)
            a_u[blk][kc] = *(const bf16x8*)(wpk + (((long)(hs*2+blk)*24 + kc)*64 + lane)*8);
        #pragma unroll
        for (int kc = 0; kc < 8; ++kc)
            a_w[blk][kc] = *(const bf16x8*)(wpk + (((long)(hs*2+blk)*24 + 16 + kc)*64 + lane)*8);
    }
    float b0[4], b1[4];
    #pragma unroll
    for (int q = 0; q < 4; ++q) {
        b0[q] = bias[g4 * H_ + hs * 8 + q];
        b1[q] = bias[g4 * H_ + hs * 8 + 4 + q];
    }
    float cst[8];
    #pragma unroll
    for (int i = 0; i < 8; ++i) cst[i] = 0.f;

    // publish slot: frag (bt, kc=hs>>2), lane slot (hs&3)*16 + c16, 16B/row
    ull* const pub0 = (ull*)hfrag +
        (((long)bt * 16 + (hs >> 2)) * 64 + ((hs & 3) * 16 + c16)) * 2;

    for (int t = 0; t < T_; ++t) {
        // h poll-loads FIRST (critical path): issue all 16 frags (2x8B each)
        ull L[16], Hh[16];
        const ull* hp = (const ull*)(hfrag + (long)(t - 1) * HB_STEP) +
                        ((long)bt * 16 * 64 + lane) * 2;
        if (t > 0) {
            #pragma unroll
            for (int kc = 0; kc < 16; ++kc) {
                L[kc]  = ald(hp + kc * 128);
                Hh[kc] = ald(hp + kc * 128 + 1);
            }
        }

        // x B-frags + x-GEMM: h-independent, overlaps the polls' round trip
        const short* xr = xfrag + (long)t * XF_STEP;
        bf16x8 xf[8];
        #pragma unroll
        for (int kc = 0; kc < 8; ++kc)
            xf[kc] = *(const bf16x8*)(xr + ((long)(bt * 8 + kc) * 64 + lane) * 8);

        f32x4 a0 = (f32x4){b0[0], b0[1], b0[2], b0[3]};
        f32x4 a1 = (f32x4){b1[0], b1[1], b1[2], b1[3]};
        #pragma unroll
        for (int kc = 0; kc < 8; ++kc) {
            a0 = __builtin_amdgcn_mfma_f32_16x16x32_bf16(a_w[0][kc], xf[kc], a0, 0, 0, 0);
            a1 = __builtin_amdgcn_mfma_f32_16x16x32_bf16(a_w[1][kc], xf[kc], a1, 0, 0, 0);
        }

        if (t > 0) {
            // Batched freshness spin: each iteration re-checks the mask and
            // re-issues ALL still-stale frag loads concurrently (~1 RT/iter).
            unsigned stale = 0xFFFFu;
            for (int guard = 0; guard < (1 << 20); ++guard) {
                unsigned ns = 0;
                #pragma unroll
                for (int kc = 0; kc < 16; ++kc) {
                    if ((stale >> kc) & 1u) {
                        if (!__all(((L[kc] | Hh[kc]) & SGN) == 0)) ns |= (1u << kc);
                    }
                }
                stale = ns;                 // wave-uniform (from __all)
                if (!stale) break;
                #pragma unroll
                for (int kc = 0; kc < 16; ++kc) {
                    if ((stale >> kc) & 1u) {
                        L[kc]  = ald(hp + kc * 128);
                        Hh[kc] = ald(hp + kc * 128 + 1);
                    }
                }
            }
            // h-GEMM (K=512), fixed order for determinism
            #pragma unroll
            for (int kc = 0; kc < 16; ++kc) {
                ullx2 u; u[0] = L[kc]; u[1] = Hh[kc];
                bf16x8 hf = __builtin_bit_cast(bf16x8, u);
                a0 = __builtin_amdgcn_mfma_f32_16x16x32_bf16(a_u[0][kc], hf, a0, 0, 0, 0);
                a1 = __builtin_amdgcn_mfma_f32_16x16x32_bf16(a_u[1][kc], hf, a1, 0, 0, 0);
            }
        }

        // Gates: lane group g4 owns gate g4; shuffle activated values so every
        // lane gets (i,f,g,o) for its (q, batch col c16) of both j-blocks.
        float hv[8];
        #pragma unroll
        for (int blk = 0; blk < 2; ++blk) {
            #pragma unroll
            for (int q = 0; q < 4; ++q) {
                float z = blk ? a1[q] : a0[q];
                float a = (g4 == 2) ? fmaxf(z, 0.f)               // candidate: relu
                                    : 1.f / (1.f + __expf(-z));   // i,f,o: sigmoid
                float ai = __shfl(a, c16,      64);
                float af = __shfl(a, c16 + 16, 64);
                float ag = __shfl(a, c16 + 32, 64);
                float ao = __shfl(a, c16 + 48, 64);
                float c_ = af * cst[blk*4+q] + ai * ag;
                cst[blk*4+q] = c_;
                hv[blk*4+q] = ao * fmaxf(c_, 0.f);
            }
        }

        if (t < T_ - 1) {
            if (g4 == 0) {   // 16 lanes publish 16B each: full-density 256B block
                ull p0 = (ull)f2bf(hv[0]) | ((ull)f2bf(hv[1])<<16)
                       | ((ull)f2bf(hv[2])<<32) | ((ull)f2bf(hv[3])<<48);
                ull p1 = (ull)f2bf(hv[4]) | ((ull)f2bf(hv[5])<<16)
                       | ((ull)f2bf(hv[6])<<32) | ((ull)f2bf(hv[7])<<48);
                ull* d = pub0 + (long)t * (HB_STEP / 4);
                ast(d, p0); ast(d + 1, p1);
            }
        } else {
            if (g4 == 0) {
                *(float4*)(hfin + ((long)bt * 16 + c16) * H_ + hs * 8)
                    = make_float4(hv[0], hv[1], hv[2], hv[3]);
                *(float4*)(hfin + ((long)bt * 16 + c16) * H_ + hs * 8 + 4)
                    = make_float4(hv[4], hv[5], hv[6], hv[7]);
            }
        }
    }
}

// ---------------- C: dense head + softmax ----------------
__global__ __launch_bounds__(256) void k_head(const float* __restrict__ hfin,
                                              const float* __restrict__ W2,
                                              const float* __restrict__ b2,
                                              const float* __restrict__ W3,
                                              const float* __restrict__ b3,
                                              float* __restrict__ out) {
    __shared__ float hs[H_];
    __shared__ float ys[U1_];
    __shared__ float ps[4][U2_];
    const int b = blockIdx.x, tid = threadIdx.x;
    if (tid < 128) *(float4*)(hs + tid * 4) = *(const float4*)(hfin + (long)b * H_ + tid * 4);
    __syncthreads();
    float acc = b2[tid];
    #pragma unroll 8
    for (int k = 0; k < H_; ++k) acc += hs[k] * W2[(long)k * U1_ + tid];
    ys[tid] = fmaxf(acc, 0.f);
    __syncthreads();
    const int u2 = tid & 63, part = tid >> 6;
    float p = 0.f;
    #pragma unroll 8
    for (int k = part * 64; k < part * 64 + 64; ++k) p += ys[k] * W3[(long)k * U2_ + u2];
    ps[part][u2] = p;
    __syncthreads();
    if (tid < 64) {
        float lg = b3[tid] + ps[0][tid] + ps[1][tid] + ps[2][tid] + ps[3][tid];
        float m = lg;
        #pragma unroll
        for (int off = 32; off >= 1; off >>= 1) m = fmaxf(m, __shfl_xor(m, off, 64));
        float e = __expf(lg - m);
        float s = e;
        #pragma unroll
        for (int off = 32; off >= 1; off >>= 1) s += __shfl_xor(s, off, 64);
        out[(long)b * U2_ + tid] = e / s;
    }
}

extern "C" void kernel_launch(void* const* d_in, const int* in_sizes, int n_in,
                              void* d_out, int out_size, void* d_ws, size_t ws_size,
                              hipStream_t stream) {
    const int*   inp = (const int*)d_in[0];
    const float* emb = (const float*)d_in[1];
    const float* W   = (const float*)d_in[2];
    const float* U   = (const float*)d_in[3];
    const float* bb  = (const float*)d_in[4];
    const float* W2  = (const float*)d_in[5];
    const float* b2  = (const float*)d_in[6];
    const float* W3  = (const float*)d_in[7];
    const float* b3  = (const float*)d_in[8];

    char* ws = (char*)d_ws;
    const long HB_BYTES = (long)(T_ - 1) * HB_STEP * 2;      // 33,292,288
    short* hfrag = (short*)ws;                                // [0, 31.75MB)
    short* xfrag = (short*)(ws + HB_BYTES);                   // 16 MiB
    short* wpk   = (short*)(ws + HB_BYTES + 16777216);        // 3 MiB
    float* hfin  = (float*)(ws + HB_BYTES + 16777216 + 3145728); // 512 KiB

    // re-poison the write-once h buffers every call (determinism across replays)
    hipMemsetAsync(hfrag, 0xAA, HB_BYTES, stream);
    k_prep<<<32, 256, 0, stream>>>(U, W, wpk);
    k_gather<<<256, 256, 0, stream>>>(inp, emb, xfrag);
    k_lstm<<<256, 256, 0, stream>>>(bb, wpk, xfrag, hfrag, hfin);
    k_head<<<B_, 256, 0, stream>>>(hfin, W2, b2, W3, b3, (float*)d_out);
}

// Round 7
// 528.580 us; speedup vs baseline: 4.4484x; 1.9885x over previous
//
#include <hip/hip_runtime.h>
#include <hip/hip_bf16.h>
#include <stdint.h>

#define B_  256
#define T_  128
#define E_  256
#define H_  512
#define G4  2048
#define U1_ 256
#define U2_ 64

#define HB_STEP   (16 * 16 * 64 * 8)   // shorts per h step-buffer (256 KB)
#define XF_STEP   (16 * 8 * 64 * 8)    // shorts per x step (128 KB)
#define SGN 0x8000800080008000ULL

typedef __attribute__((ext_vector_type(8))) short bf16x8;
typedef __attribute__((ext_vector_type(4))) float f32x4;
typedef __attribute__((ext_vector_type(2))) unsigned long long ullx2;
typedef unsigned long long ull;

static __device__ __forceinline__ unsigned short f2bf(float f) {
    unsigned u = __float_as_uint(f);
    unsigned r = (u + 0x7FFFu + ((u >> 16) & 1u)) >> 16;   // RNE
    return (unsigned short)r;
}
static __device__ __forceinline__ ull ald(const ull* p) {
    return __hip_atomic_load(p, __ATOMIC_RELAXED, __HIP_MEMORY_SCOPE_AGENT);
}
static __device__ __forceinline__ void ast(ull* p, ull v) {
    __hip_atomic_store(p, v, __ATOMIC_RELAXED, __HIP_MEMORY_SCOPE_AGENT);
}

// ---------- A0: pack U,W (f32 row-major) into bf16 MFMA A-frag layout ----------
__global__ __launch_bounds__(256) void k_prep(const float* __restrict__ U,
                                              const float* __restrict__ W,
                                              short* __restrict__ wpk) {
    __shared__ float ld[32][64];
    const int bj = blockIdx.x;          // 0..31: (gate, 64-wide j window)
    const int g  = bj >> 3;
    const int l0 = (bj & 7) * 64;
    const int t  = threadIdx.x;
    const int p   = t >> 4;             // 0..15 -> (hs_local, blk)
    const int hsl = p >> 1, blk = p & 1;
    const int ci  = t & 3;
    const int g4w = (t >> 2) & 3;
    const int hs  = (l0 >> 3) + hsl;
    const int c16 = g * 4 + ci;
    const int jloc = hsl * 8 + blk * 4 + ci;
    for (int kc = 0; kc < 24; ++kc) {
        const float* src = (kc < 16) ? (U + (long)(kc * 32) * G4)
                                     : (W + (long)((kc - 16) * 32) * G4);
        #pragma unroll
        for (int r = 0; r < 8; ++r) {
            int row = r * 4 + (t >> 6);
            ld[row][t & 63] = src[(long)row * G4 + g * 512 + l0 + (t & 63)];
        }
        __syncthreads();
        bf16x8 o;
        #pragma unroll
        for (int e = 0; e < 8; ++e) o[e] = (short)f2bf(ld[g4w * 8 + e][jloc]);
        *(bf16x8*)(wpk + (((long)(hs * 2 + blk) * 24 + kc) * 64 + (g4w * 16 + c16)) * 8) = o;
        __syncthreads();
    }
}

// ---------- A1: gather embeddings -> x in MFMA B-frag layout (bf16) ----------
__global__ __launch_bounds__(256) void k_gather(const int* __restrict__ inp,
                                                const float* __restrict__ emb,
                                                short* __restrict__ xfrag) {
    const int tid  = threadIdx.x;
    const int wv   = tid >> 6;
    const int lane = tid & 63;
    const int c16  = lane & 15;
    const int g4   = lane >> 4;
    for (int it = 0; it < 16; ++it) {
        int task  = (it * 256 + blockIdx.x) * 4 + wv;   // t*128 + btile*8 + kc
        int kc    = task & 7;
        int btile = (task >> 3) & 15;
        int t     = task >> 7;
        int b     = btile * 16 + c16;
        int idx   = inp[b * T_ + t];
        const float* src = emb + (long)idx * E_ + kc * 32 + g4 * 8;
        float4 v0 = *(const float4*)src;
        float4 v1 = *(const float4*)(src + 4);
        bf16x8 o;
        o[0]=(short)f2bf(v0.x); o[1]=(short)f2bf(v0.y); o[2]=(short)f2bf(v0.z); o[3]=(short)f2bf(v0.w);
        o[4]=(short)f2bf(v1.x); o[5]=(short)f2bf(v1.y); o[6]=(short)f2bf(v1.z); o[7]=(short)f2bf(v1.w);
        *(bf16x8*)(xfrag + ((long)((t * 16 + btile) * 8 + kc) * 64 + lane) * 8) = o;
    }
}

// ---------------- B: persistent recurrent kernel, pure dataflow ----------------
// WG = (bt, hsg): all 4 waves share batch-tile bt; wave wv owns hidden slice
// hs = hsg*4+wv (8 units). 16 independent per-bt pipelines of 16 WGs each.
// Frag (bt,kc) is produced ENTIRELY by WG (bt,kc) (write-once, 0xAA-poisoned;
// h >= 0 so clear bf16 sign == fresh at any tearing granularity; 8B atomic
// store/load pairs can't tear sub-8B). Each wave polls 4 frags from L3
// (agent loads), stages to LDS; all waves consume via ds_read -> L3 poll
// traffic cut 4x vs per-wave polling. Own frag bypasses L3 (direct LDS write).
__global__ __launch_bounds__(256, 1) void k_lstm(
    const float* __restrict__ bias,   // [G4]
    const short* __restrict__ wpk,    // packed A-frags
    const short* __restrict__ xfrag,  // [T_][16][8][64][8] bf16
    short* hfrag,                     // [T_-1][16][16][64][8] bf16, poisoned
    float* hfin)                      // [B_][H_] f32
{
    __shared__ short lds[2][16][64][8];   // 2 x 16 KB h-frag buffers
    const int tid  = threadIdx.x;
    const int wid  = blockIdx.x;      // 0..255
    const int bt   = wid >> 4;        // batch tile 0..15 (16 rows)
    const int hsg  = wid & 15;        // hidden-slice group; owns frag kc=hsg
    const int lane = tid & 63;
    const int wv   = tid >> 6;
    const int hs   = hsg * 4 + wv;    // this wave's hidden slice (8 units)
    const int c16  = lane & 15;
    const int g4   = lane >> 4;
    const int selfj = ((hsg >> 2) == wv) ? (hsg & 3) : -1;   // wave-uniform

    // Persistent A-frags, coalesced load from wpk (2 j-blocks x (16 U + 8 W))
    bf16x8 a_u[2][16], a_w[2][8];
    #pragma unroll
    for (int blk = 0; blk < 2; ++blk) {
        #pragma unroll
        for (int kc = 0; kc < 16; ++kc)
            a_u[blk][kc] = *(const bf16x8*)(wpk + (((long)(hs*2+blk)*24 + kc)*64 + lane)*8);
        #pragma unroll
        for (int kc = 0; kc < 8; ++kc)
            a_w[blk][kc] = *(const bf16x8*)(wpk + (((long)(hs*2+blk)*24 + 16 + kc)*64 + lane)*8);
    }
    float b0[4], b1[4];
    #pragma unroll
    for (int q = 0; q < 4; ++q) {
        b0[q] = bias[g4 * H_ + hs * 8 + q];
        b1[q] = bias[g4 * H_ + hs * 8 + 4 + q];
    }
    float cst[8];
    #pragma unroll
    for (int i = 0; i < 8; ++i) cst[i] = 0.f;

    // L3 publish slot: frag (bt, hsg), lane slot wv*16 + c16 (same algebra as
    // verified r5 mapping: hs>>2==hsg, hs&3==wv)
    ull* const pub0 = (ull*)hfrag + (((long)bt * 16 + hsg) * 64 + wv * 16 + c16) * 2;

    for (int t = 0; t < T_; ++t) {
        const int cb = t & 1;
        // 1) issue polls for this wave's 4 assigned frags (kc = wv*4+j)
        ull L[4] = {0,0,0,0}, Hh[4] = {0,0,0,0};
        const ull* hp = (const ull*)hfrag + ((long)(t - 1) * HB_STEP) / 4;
        if (t > 0) {
            #pragma unroll
            for (int j = 0; j < 4; ++j) {
                const ull* p = hp + (((long)bt * 16 + (wv * 4 + j)) * 64 + lane) * 2;
                L[j]  = ald(p);
                Hh[j] = ald(p + 1);
            }
        }

        // 2) x B-frags + x-GEMM: h-independent, overlaps the polls' round trip
        const short* xr = xfrag + (long)t * XF_STEP;
        bf16x8 xf[8];
        #pragma unroll
        for (int kc = 0; kc < 8; ++kc)
            xf[kc] = *(const bf16x8*)(xr + ((long)(bt * 8 + kc) * 64 + lane) * 8);

        f32x4 a0 = (f32x4){b0[0], b0[1], b0[2], b0[3]};
        f32x4 a1 = (f32x4){b1[0], b1[1], b1[2], b1[3]};
        #pragma unroll
        for (int kc = 0; kc < 8; ++kc) {
            a0 = __builtin_amdgcn_mfma_f32_16x16x32_bf16(a_w[0][kc], xf[kc], a0, 0, 0, 0);
            a1 = __builtin_amdgcn_mfma_f32_16x16x32_bf16(a_w[1][kc], xf[kc], a1, 0, 0, 0);
        }

        if (t > 0) {
            // 3) batched freshness spin on the (up to) 4 polled frags;
            //    self frag excluded (comes via LDS from our own t-1 write)
            unsigned stale = 0xFu & ~((selfj >= 0) ? (1u << selfj) : 0u);
            for (int guard = 0; guard < (1 << 20); ++guard) {
                unsigned ns = 0;
                #pragma unroll
                for (int j = 0; j < 4; ++j) {
                    if ((stale >> j) & 1u) {
                        if (!__all(((L[j] | Hh[j]) & SGN) == 0)) ns |= (1u << j);
                    }
                }
                stale = ns;                 // wave-uniform (from __all)
                if (!stale) break;
                #pragma unroll
                for (int j = 0; j < 4; ++j) {
                    if ((stale >> j) & 1u) {
                        const ull* p = hp + (((long)bt * 16 + (wv * 4 + j)) * 64 + lane) * 2;
                        L[j]  = ald(p);
                        Hh[j] = ald(p + 1);
                    }
                }
            }
            // 4) stage polled frags into LDS (skip self)
            #pragma unroll
            for (int j = 0; j < 4; ++j) {
                if (j != selfj) {
                    ullx2 u; u[0] = L[j]; u[1] = Hh[j];
                    *(ullx2*)(&lds[cb][wv * 4 + j][lane][0]) = u;
                }
            }
        }
        __syncthreads();

        // 5) h-GEMM (K=512) from LDS, fixed kc order for determinism
        if (t > 0) {
            #pragma unroll
            for (int kc = 0; kc < 16; ++kc) {
                bf16x8 hf = *(const bf16x8*)(&lds[cb][kc][lane][0]);
                a0 = __builtin_amdgcn_mfma_f32_16x16x32_bf16(a_u[0][kc], hf, a0, 0, 0, 0);
                a1 = __builtin_amdgcn_mfma_f32_16x16x32_bf16(a_u[1][kc], hf, a1, 0, 0, 0);
            }
        }

        // 6) gates: lane group g4 owns gate g4; shuffle so every lane gets
        //    (i,f,g,o) for its (q, batch col c16) of both j-blocks.
        float hv[8];
        #pragma unroll
        for (int blk = 0; blk < 2; ++blk) {
            #pragma unroll
            for (int q = 0; q < 4; ++q) {
                float z = blk ? a1[q] : a0[q];
                float a = (g4 == 2) ? fmaxf(z, 0.f)               // candidate: relu
                                    : 1.f / (1.f + __expf(-z));   // i,f,o: sigmoid
                float ai = __shfl(a, c16,      64);
                float af = __shfl(a, c16 + 16, 64);
                float ag = __shfl(a, c16 + 32, 64);
                float ao = __shfl(a, c16 + 48, 64);
                float c_ = af * cst[blk*4+q] + ai * ag;
                cst[blk*4+q] = c_;
                hv[blk*4+q] = ao * fmaxf(c_, 0.f);
            }
        }

        // 7) publish h(t): L3 (for the other 15 WGs) + own LDS (next step)
        if (t < T_ - 1) {
            if (g4 == 0) {
                ull p0 = (ull)f2bf(hv[0]) | ((ull)f2bf(hv[1])<<16)
                       | ((ull)f2bf(hv[2])<<32) | ((ull)f2bf(hv[3])<<48);
                ull p1 = (ull)f2bf(hv[4]) | ((ull)f2bf(hv[5])<<16)
                       | ((ull)f2bf(hv[6])<<32) | ((ull)f2bf(hv[7])<<48);
                ull* d = pub0 + (long)t * (HB_STEP / 4);
                ast(d, p0); ast(d + 1, p1);
                ullx2 u; u[0] = p0; u[1] = p1;
                *(ullx2*)(&lds[(t + 1) & 1][hsg][wv * 16 + c16][0]) = u;
            }
        } else {
            if (g4 == 0) {
                *(float4*)(hfin + ((long)bt * 16 + c16) * H_ + hs * 8)
                    = make_float4(hv[0], hv[1], hv[2], hv[3]);
                *(float4*)(hfin + ((long)bt * 16 + c16) * H_ + hs * 8 + 4)
                    = make_float4(hv[4], hv[5], hv[6], hv[7]);
            }
        }
    }
}

// ---------------- C: dense head + softmax ----------------
__global__ __launch_bounds__(256) void k_head(const float* __restrict__ hfin,
                                              const float* __restrict__ W2,
                                              const float* __restrict__ b2,
                                              const float* __restrict__ W3,
                                              const float* __restrict__ b3,
                                              float* __restrict__ out) {
    __shared__ float hs[H_];
    __shared__ float ys[U1_];
    __shared__ float ps[4][U2_];
    const int b = blockIdx.x, tid = threadIdx.x;
    if (tid < 128) *(float4*)(hs + tid * 4) = *(const float4*)(hfin + (long)b * H_ + tid * 4);
    __syncthreads();
    float acc = b2[tid];
    #pragma unroll 8
    for (int k = 0; k < H_; ++k) acc += hs[k] * W2[(long)k * U1_ + tid];
    ys[tid] = fmaxf(acc, 0.f);
    __syncthreads();
    const int u2 = tid & 63, part = tid >> 6;
    float p = 0.f;
    #pragma unroll 8
    for (int k = part * 64; k < part * 64 + 64; ++k) p += ys[k] * W3[(long)k * U2_ + u2];
    ps[part][u2] = p;
    __syncthreads();
    if (tid < 64) {
        float lg = b3[tid] + ps[0][tid] + ps[1][tid] + ps[2][tid] + ps[3][tid];
        float m = lg;
        #pragma unroll
        for (int off = 32; off >= 1; off >>= 1) m = fmaxf(m, __shfl_xor(m, off, 64));
        float e = __expf(lg - m);
        float s = e;
        #pragma unroll
        for (int off = 32; off >= 1; off >>= 1) s += __shfl_xor(s, off, 64);
        out[(long)b * U2_ + tid] = e / s;
    }
}

extern "C" void kernel_launch(void* const* d_in, const int* in_sizes, int n_in,
                              void* d_out, int out_size, void* d_ws, size_t ws_size,
                              hipStream_t stream) {
    const int*   inp = (const int*)d_in[0];
    const float* emb = (const float*)d_in[1];
    const float* W   = (const float*)d_in[2];
    const float* U   = (const float*)d_in[3];
    const float* bb  = (const float*)d_in[4];
    const float* W2  = (const float*)d_in[5];
    const float* b2  = (const float*)d_in[6];
    const float* W3  = (const float*)d_in[7];
    const float* b3  = (const float*)d_in[8];

    char* ws = (char*)d_ws;
    const long HB_BYTES = (long)(T_ - 1) * HB_STEP * 2;      // 33,292,288
    short* hfrag = (short*)ws;                                // [0, 31.75MB)
    short* xfrag = (short*)(ws + HB_BYTES);                   // 16 MiB
    short* wpk   = (short*)(ws + HB_BYTES + 16777216);        // 3 MiB
    float* hfin  = (float*)(ws + HB_BYTES + 16777216 + 3145728); // 512 KiB

    // re-poison the write-once h buffers every call (determinism across replays)
    hipMemsetAsync(hfrag, 0xAA, HB_BYTES, stream);
    k_prep<<<32, 256, 0, stream>>>(U, W, wpk);
    k_gather<<<256, 256, 0, stream>>>(inp, emb, xfrag);
    k_lstm<<<256, 256, 0, stream>>>(bb, wpk, xfrag, hfrag, hfin);
    k_head<<<B_, 256, 0, stream>>>(hfin, W2, b2, W3, b3, (float*)d_out);
}